// Round 14
// baseline (178.677 us; speedup 1.0000x reference)
//
#include <hip/hip_runtime.h>
#include <hip/hip_bf16.h>

// MHA: B=2, T=2048, D=1024, H=16, DH=64. fp32 in/out, bf16 MFMA internal.
// R25 = R24 + XCD-locality swizzles (T1, index-remap only):
//      - attn: bh=(id%8)*4+((id>>3)&3), j=id>>5  -> each XCD owns 4 heads
//        (2MB K/V L2-resident vs 16MB churn). Big-jobs-first preserved.
//      - gemm_qkv: chunked nid=(id%8)*96+id/8 -> 3 n-columns per XCD
//        (B-panel 1x per L2 instead of 8x duplicated).
//      - gemm_out: nid=(id%8)*64+id/8.
//      All compute/layout/sync byte-identical to R24.

typedef __bf16 bf16x8 __attribute__((ext_vector_type(8)));
typedef __bf16 bf16x4 __attribute__((ext_vector_type(4)));
typedef float  f32x4  __attribute__((ext_vector_type(4)));

#define Bx 2
#define Tx 2048
#define Dx 1024
#define Hx 16
#define DHx 64

// job table: {chunk, firstTile, nTiles}, descending nTiles. 47 jobs per (b,h).
__device__ __constant__ unsigned char JTAB[47][3] = {
    {16, 0, 17},
    {31, 0, 16}, {31, 16, 16}, {30, 0, 16}, {15, 0, 16},
    {30, 16, 15}, {29, 0, 15}, {29, 15, 15}, {28, 0, 15}, {14, 0, 15},
    {28, 15, 14}, {27, 0, 14}, {27, 14, 14}, {26, 0, 14}, {13, 0, 14},
    {26, 14, 13}, {25, 0, 13}, {25, 13, 13}, {24, 0, 13}, {12, 0, 13},
    {24, 13, 12}, {23, 0, 12}, {23, 12, 12}, {22, 0, 12}, {11, 0, 12},
    {22, 12, 11}, {21, 0, 11}, {21, 11, 11}, {20, 0, 11}, {10, 0, 11},
    {20, 11, 10}, {19, 0, 10}, {19, 10, 10}, {18, 0, 10}, {9, 0, 10},
    {18, 10, 9}, {17, 0, 9}, {17, 9, 9}, {8, 0, 9},
    {7, 0, 8}, {6, 0, 7}, {5, 0, 6}, {4, 0, 5}, {3, 0, 4}, {2, 0, 3},
    {1, 0, 2}, {0, 0, 1}
};

// ---------------- prep: z=0 -> x fp32->bf16; z=1..4 -> W transpose+cvt ----------------
__global__ __launch_bounds__(256) void prep(const float* __restrict__ x,
                                            const float* __restrict__ W0,
                                            const float* __restrict__ W1,
                                            const float* __restrict__ W2,
                                            const float* __restrict__ W3,
                                            __bf16* __restrict__ xb,
                                            __bf16* __restrict__ Wt) {
    const int z = blockIdx.z;
    if (z == 0) {
        const int blk = blockIdx.y * 16 + blockIdx.x;
        const float* xp = x + (size_t)blk * 16384;
        __bf16* xo = xb + (size_t)blk * 16384;
#pragma unroll
        for (int i = 0; i < 16; i++) {
            float4 v = *(const float4*)(xp + i * 1024 + threadIdx.x * 4);
            bf16x4 o;
            o[0] = (__bf16)v.x; o[1] = (__bf16)v.y; o[2] = (__bf16)v.z; o[3] = (__bf16)v.w;
            *(bf16x4*)(xo + i * 1024 + threadIdx.x * 4) = o;
        }
        return;
    }
    __shared__ float tile[64][65];
    const float* W = (z == 1) ? W0 : (z == 2) ? W1 : (z == 3) ? W2 : W3;
    __bf16* o = Wt + (size_t)(z - 1) * Dx * Dx;
    int k0 = blockIdx.x * 64, n0 = blockIdx.y * 64;
    int t = threadIdx.x;
    int cc = t & 63, rbase = t >> 6;
#pragma unroll
    for (int i = 0; i < 16; i++) {
        int rr = rbase + i * 4;
        tile[rr][cc] = W[(size_t)(k0 + rr) * Dx + n0 + cc];
    }
    __syncthreads();
#pragma unroll
    for (int i = 0; i < 16; i++) {
        int rr = rbase + i * 4;
        o[(size_t)(n0 + rr) * Dx + k0 + cc] = (__bf16)tile[cc][rr];
    }
}

static __device__ __forceinline__ void gload16(const __bf16* g, __bf16* l) {
    __builtin_amdgcn_global_load_lds((const __attribute__((address_space(1))) void*)g,
                                     (__attribute__((address_space(3))) void*)l, 16, 0, 0);
}

// swizzled LDS address: [row][colByte] with byte-XOR (row&7)<<4; rows are 128B.
static __device__ __forceinline__ char* swzp(char* base, int row, int colByte) {
    return base + row * 128 + (colByte ^ ((row & 7) << 4));
}

// ---------------- fused QKV GEMM: [4096 x 3072] = xb @ [WqT;WkT;WvT]^T ----------------
// 128x128 tile, BK=64 as 2 BK=32 halves. 4 waves, each owns a 64x64 quadrant.
__global__ __launch_bounds__(256, 3) void gemm_qkv(const __bf16* __restrict__ A,
                                                   const __bf16* __restrict__ BT,
                                                   __bf16* __restrict__ Qb,
                                                   __bf16* __restrict__ Kb,
                                                   __bf16* __restrict__ Vt) {
    __shared__ __bf16 As[2][128 * 32];  // 16 KB (two k-halves)
    __shared__ __bf16 Bs[2][128 * 32];  // 16 KB
    __shared__ __bf16 Vbuf[64 * 136];   // 17 KB epilogue transpose (z==2)
    const int t = threadIdx.x;
    const int lane = t & 63, wave = t >> 6;
    const int lane15 = lane & 15, quad = lane >> 4;
    // XCD-chunked remap: 768 blocks, 96/XCD -> each XCD gets 3 full n-columns.
    const int id = blockIdx.x + gridDim.x * blockIdx.y;
    const int nid = (id & 7) * 96 + (id >> 3);
    const int m0 = (nid & 31) * 128, n0 = (nid >> 5) * 128;
    const int wm = wave & 1, wn = wave >> 1;

    const int sr = wave * 16 + (lane >> 2);  // 0..63 (pass 0); pass 1 adds 64
    const int sc = (lane & 3) * 8;
    const __bf16* Ag = A + (size_t)(m0 + sr) * Dx + sc;
    const __bf16* Bg = BT + (size_t)(n0 + sr) * Dx + sc;
    __bf16* As00 = &As[0][(wave * 16) * 32];
    __bf16* As01 = &As[0][(64 + wave * 16) * 32];
    __bf16* As10 = &As[1][(wave * 16) * 32];
    __bf16* As11 = &As[1][(64 + wave * 16) * 32];
    __bf16* Bs00 = &Bs[0][(wave * 16) * 32];
    __bf16* Bs01 = &Bs[0][(64 + wave * 16) * 32];
    __bf16* Bs10 = &Bs[1][(wave * 16) * 32];
    __bf16* Bs11 = &Bs[1][(64 + wave * 16) * 32];

    f32x4 acc[4][4];
#pragma unroll
    for (int i = 0; i < 4; i++)
#pragma unroll
        for (int j = 0; j < 4; j++) acc[i][j] = (f32x4){0.f, 0.f, 0.f, 0.f};

    for (int k0 = 0; k0 < Dx; k0 += 64) {
        gload16(Ag, As00);
        gload16(Ag + 64 * Dx, As01);
        gload16(Ag + 32, As10);
        gload16(Ag + 64 * Dx + 32, As11);
        gload16(Bg, Bs00);
        gload16(Bg + 64 * Dx, Bs01);
        gload16(Bg + 32, Bs10);
        gload16(Bg + 64 * Dx + 32, Bs11);
        Ag += 64; Bg += 64;
        __syncthreads();
#pragma unroll
        for (int half = 0; half < 2; half++) {
            bf16x8 af[4], bfr[4];
#pragma unroll
            for (int i = 0; i < 4; i++)
                af[i] = *(const bf16x8*)&As[half][(wm * 64 + i * 16 + lane15) * 32 + quad * 8];
#pragma unroll
            for (int j = 0; j < 4; j++)
                bfr[j] = *(const bf16x8*)&Bs[half][(wn * 64 + j * 16 + lane15) * 32 + quad * 8];
#pragma unroll
            for (int mt = 0; mt < 4; mt++)
#pragma unroll
                for (int nt = 0; nt < 4; nt++)
                    acc[mt][nt] = __builtin_amdgcn_mfma_f32_16x16x32_bf16(af[mt], bfr[nt], acc[mt][nt], 0, 0, 0);
        }
        __syncthreads();
    }

    const int z = n0 >> 10;  // block n-range lies in one z (128 | 1024)
    if (z < 2) {
        __bf16* outp = z ? Kb : Qb;
        // Q pre-scaled by 0.125 * log2(e) so attn can use exp2 directly.
        const float scale = z ? 1.0f : 0.18033688011112042f;
#pragma unroll
        for (int mt = 0; mt < 4; mt++)
#pragma unroll
            for (int nt = 0; nt < 4; nt++) {
                const int cc = (n0 + wn * 64 + nt * 16 + lane15) & 1023;
                const int h = cc >> 6, dh = cc & 63;
#pragma unroll
                for (int r4 = 0; r4 < 4; r4++) {
                    const int row = m0 + wm * 64 + mt * 16 + quad * 4 + r4;
                    const int b = row >> 11, tt = row & 2047;
                    outp[(((size_t)(b * Hx + h) * Tx + tt) << 6) + dh] =
                        (__bf16)(acc[mt][nt][r4] * scale);
                }
            }
    } else {
        // V^T epilogue via LDS transpose: coalesced 64B-per-thread stores.
        const int bq = m0 >> 11;
        const int tt0 = m0 & 2047;
#pragma unroll
        for (int p = 0; p < 2; p++) {
            if (p) __syncthreads();  // pass-0 readers done before buffer reuse
            if (wn == p) {
#pragma unroll
                for (int mt = 0; mt < 4; mt++)
#pragma unroll
                    for (int nt = 0; nt < 4; nt++) {
                        bf16x4 v4;
#pragma unroll
                        for (int r4 = 0; r4 < 4; r4++) v4[r4] = (__bf16)acc[mt][nt][r4];
                        *(bf16x4*)&Vbuf[(nt * 16 + lane15) * 136 + wm * 64 + mt * 16 + quad * 4] = v4;
                    }
            }
            __syncthreads();  // tile visible
            const int row = t >> 2;          // 0..63: local column (dh-line)
            const int part = (t & 3) * 32;   // 32 elems = 64B per thread
            const int cf = (n0 + p * 64 + row) & 1023;
            const int h = cf >> 6, dh = cf & 63;
            __bf16* dst = Vt + ((size_t)(bq * Hx + h) * DHx + dh) * Tx + tt0 + part;
            const __bf16* srcl = &Vbuf[row * 136 + part];
#pragma unroll
            for (int i = 0; i < 4; i++)
                *(bf16x8*)(dst + i * 8) = *(const bf16x8*)(srcl + i * 8);
        }
    }
}

// ---------------- output GEMM: out[4096 x 1024] = ctx @ Wo + bo ----------------
__global__ __launch_bounds__(256, 2) void gemm_out(const __bf16* __restrict__ A,
                                                   const __bf16* __restrict__ BT,
                                                   float* __restrict__ outf,
                                                   const float* __restrict__ bias) {
    __shared__ __bf16 As[2][128 * 32];  // 16 KB
    __shared__ __bf16 Bs[2][64 * 32];   // 8 KB
    const int t = threadIdx.x;
    const int lane = t & 63, wave = t >> 6;
    const int lane15 = lane & 15, quad = lane >> 4;
    // XCD-chunked remap: 512 blocks, 64/XCD -> each XCD gets 2 full n-columns.
    const int id = blockIdx.x + gridDim.x * blockIdx.y;
    const int nid = (id & 7) * 64 + (id >> 3);
    const int m0 = (nid & 31) * 128, n0 = (nid >> 5) * 64;
    const int wm = wave & 1, wn = wave >> 1;

    const int sr = wave * 16 + (lane >> 2), sc = (lane & 3) * 8;
    const __bf16* Ag = A + (size_t)(m0 + sr) * Dx + sc;
    const __bf16* Bg = BT + (size_t)(n0 + sr) * Dx + sc;
    __bf16* As00 = &As[0][(wave * 16) * 32];
    __bf16* As01 = &As[0][(64 + wave * 16) * 32];
    __bf16* As10 = &As[1][(wave * 16) * 32];
    __bf16* As11 = &As[1][(64 + wave * 16) * 32];
    __bf16* Bs0  = &Bs[0][(wave * 16) * 32];
    __bf16* Bs1  = &Bs[1][(wave * 16) * 32];

    f32x4 acc[4][2];
#pragma unroll
    for (int i = 0; i < 4; i++)
#pragma unroll
        for (int j = 0; j < 2; j++) acc[i][j] = (f32x4){0.f, 0.f, 0.f, 0.f};

    for (int k0 = 0; k0 < Dx; k0 += 64) {
        gload16(Ag, As00);
        gload16(Ag + 64 * Dx, As01);
        gload16(Ag + 32, As10);
        gload16(Ag + 64 * Dx + 32, As11);
        gload16(Bg, Bs0);
        gload16(Bg + 32, Bs1);
        Ag += 64; Bg += 64;
        __syncthreads();
#pragma unroll
        for (int half = 0; half < 2; half++) {
            bf16x8 af[4], bfr[2];
#pragma unroll
            for (int i = 0; i < 4; i++)
                af[i] = *(const bf16x8*)&As[half][(wm * 64 + i * 16 + lane15) * 32 + quad * 8];
#pragma unroll
            for (int j = 0; j < 2; j++)
                bfr[j] = *(const bf16x8*)&Bs[half][(wn * 32 + j * 16 + lane15) * 32 + quad * 8];
#pragma unroll
            for (int mt = 0; mt < 4; mt++)
#pragma unroll
                for (int nt = 0; nt < 2; nt++)
                    acc[mt][nt] = __builtin_amdgcn_mfma_f32_16x16x32_bf16(af[mt], bfr[nt], acc[mt][nt], 0, 0, 0);
        }
        __syncthreads();
    }

#pragma unroll
    for (int mt = 0; mt < 4; mt++)
#pragma unroll
        for (int nt = 0; nt < 2; nt++) {
            const int col = n0 + wn * 32 + nt * 16 + lane15;
#pragma unroll
            for (int r4 = 0; r4 < 4; r4++) {
                const int row = m0 + wm * 64 + mt * 16 + quad * 4 + r4;
                outf[(size_t)row * Dx + col] = acc[mt][nt][r4] + bias[col];
            }
        }
}

// ---------------- MFMA flash attention: split-K jobs, XOR-swizzled LDS, XCD-clustered heads ----------------
__global__ __launch_bounds__(256) void attn_mfma(const __bf16* __restrict__ Q,
                                                 const __bf16* __restrict__ K,
                                                 const __bf16* __restrict__ Vt,
                                                 __bf16* __restrict__ ctx,
                                                 float* __restrict__ o0w,
                                                 float* __restrict__ o1w,
                                                 float* __restrict__ lw) {
    __shared__ __bf16 Ks[64 * 64];   // [key][d]   8 KB, swizzled
    __shared__ __bf16 Vs[64 * 64];   // [d][key]   8 KB, swizzled
    __shared__ __bf16 Ps[64 * 64];   // [q][key]   8 KB, swizzled
    const int t = threadIdx.x;
    const int lane = t & 63, wave = t >> 6;
    const int lane15 = lane & 15, quad = lane >> 4;
    const int id = blockIdx.x;           // 0..1503
    // XCD-clustered head mapping: same bh -> same id%8 (XCD); big jobs first (j=id>>5).
    const int bh = (id & 7) * 4 + ((id >> 3) & 3);
    const int j = id >> 5;
    const int c = JTAB[j][0];
    const int t0 = JTAB[j][1];
    const int ktend = t0 + JTAB[j][2];
    const bool single = (t0 == 0) && (ktend == c + 1);
    const int b = bh >> 4, h = bh & 15;
    const int q0 = c * 64;
    const int qg = q0 + wave * 16 + quad * 4;
    const size_t headoff = ((size_t)(b * Hx + h)) * Tx * DHx;
    const __bf16* Kbase = K + headoff;   // [t][d]
    const __bf16* Vbase = Vt + headoff;  // [d][t]
    const int sr = t >> 2;               // staging row 0..63
    const int sce = (t & 3) * 16;        // staging col (elems)
    const int scB = sce * 2;
    char* KsB = (char*)Ks;
    char* VsB = (char*)Vs;
    char* PsB = (char*)Ps;

    bf16x8 qf0, qf1;
    {
        const __bf16* Qp = Q + headoff + (size_t)(q0 + wave * 16 + lane15) * 64 + quad * 8;
        qf0 = *(const bf16x8*)Qp;
        qf1 = *(const bf16x8*)(Qp + 32);
    }
    f32x4 o[4];
#pragma unroll
    for (int i = 0; i < 4; i++) o[i] = (f32x4){0.f, 0.f, 0.f, 0.f};
    float lpart[4] = {0.f, 0.f, 0.f, 0.f};

    bf16x8 kpre0, kpre1, vpre0, vpre1;
    {
        const __bf16* Kp = Kbase + (size_t)(t0 * 64 + sr) * 64 + sce;
        kpre0 = *(const bf16x8*)Kp; kpre1 = *(const bf16x8*)(Kp + 8);
        const __bf16* Vp = Vbase + (size_t)sr * Tx + t0 * 64 + sce;
        vpre0 = *(const bf16x8*)Vp; vpre1 = *(const bf16x8*)(Vp + 8);
    }

    for (int kt = t0; kt < ktend; kt++) {
        __syncthreads();  // prior tile's LDS reads complete
        *(bf16x8*)swzp(KsB, sr, scB)      = kpre0;
        *(bf16x8*)swzp(KsB, sr, scB + 16) = kpre1;
        *(bf16x8*)swzp(VsB, sr, scB)      = vpre0;
        *(bf16x8*)swzp(VsB, sr, scB + 16) = vpre1;
        if (kt + 1 < ktend) {
            const __bf16* Kp = Kbase + (size_t)((kt + 1) * 64 + sr) * 64 + sce;
            kpre0 = *(const bf16x8*)Kp; kpre1 = *(const bf16x8*)(Kp + 8);
            const __bf16* Vp = Vbase + (size_t)sr * Tx + (kt + 1) * 64 + sce;
            vpre0 = *(const bf16x8*)Vp; vpre1 = *(const bf16x8*)(Vp + 8);
        }
        __syncthreads();

        f32x4 s[4];
        __builtin_amdgcn_s_setprio(1);
#pragma unroll
        for (int nt = 0; nt < 4; nt++) {
            s[nt] = (f32x4){0.f, 0.f, 0.f, 0.f};
            bf16x8 b0 = *(const bf16x8*)swzp(KsB, nt * 16 + lane15, quad * 16);
            s[nt] = __builtin_amdgcn_mfma_f32_16x16x32_bf16(qf0, b0, s[nt], 0, 0, 0);
            bf16x8 b1 = *(const bf16x8*)swzp(KsB, nt * 16 + lane15, 64 + quad * 16);
            s[nt] = __builtin_amdgcn_mfma_f32_16x16x32_bf16(qf1, b1, s[nt], 0, 0, 0);
        }
        __builtin_amdgcn_s_setprio(0);

        if (kt == c) {
            // diagonal tile: causal mask active
            const int kbase = kt * 64;
#pragma unroll
            for (int nt = 0; nt < 4; nt++)
#pragma unroll
                for (int reg = 0; reg < 4; reg++) {
                    float e = __builtin_amdgcn_exp2f(s[nt][reg]);
                    if (kbase + nt * 16 + lane15 > qg + reg) e = 0.f;
                    lpart[reg] += e;
                    *(__bf16*)swzp(PsB, wave * 16 + quad * 4 + reg,
                                   (nt * 16 + lane15) * 2) = (__bf16)e;
                }
        } else {
            // interior tile: no masking possible
#pragma unroll
            for (int nt = 0; nt < 4; nt++)
#pragma unroll
                for (int reg = 0; reg < 4; reg++) {
                    float e = __builtin_amdgcn_exp2f(s[nt][reg]);
                    lpart[reg] += e;
                    *(__bf16*)swzp(PsB, wave * 16 + quad * 4 + reg,
                                   (nt * 16 + lane15) * 2) = (__bf16)e;
                }
        }

        bf16x8 pa0 = *(const bf16x8*)swzp(PsB, wave * 16 + lane15, quad * 16);
        bf16x8 pa1 = *(const bf16x8*)swzp(PsB, wave * 16 + lane15, 64 + quad * 16);
        __builtin_amdgcn_s_setprio(1);
#pragma unroll
        for (int dt = 0; dt < 4; dt++) {
            bf16x8 vb0 = *(const bf16x8*)swzp(VsB, dt * 16 + lane15, quad * 16);
            o[dt] = __builtin_amdgcn_mfma_f32_16x16x32_bf16(pa0, vb0, o[dt], 0, 0, 0);
            bf16x8 vb1 = *(const bf16x8*)swzp(VsB, dt * 16 + lane15, 64 + quad * 16);
            o[dt] = __builtin_amdgcn_mfma_f32_16x16x32_bf16(pa1, vb1, o[dt], 0, 0, 0);
        }
        __builtin_amdgcn_s_setprio(0);
    }

    // ---- row-sum of l across the 16-lane key groups ----
    float lsum[4];
#pragma unroll
    for (int reg = 0; reg < 4; reg++) {
        float l = lpart[reg];
#pragma unroll
        for (int off = 1; off < 16; off <<= 1) l += __shfl_xor(l, off);
        lsum[reg] = l;
    }

    if (single) {
        // chunks 0..16: full key range in this job -> normalized ctx write
#pragma unroll
        for (int dt = 0; dt < 4; dt++)
#pragma unroll
            for (int reg = 0; reg < 4; reg++) {
                int q = q0 + wave * 16 + quad * 4 + reg;
                ctx[(((size_t)(b * Tx + q)) * Hx + h) * 64 + dt * 16 + lane15] =
                    (__bf16)(o[dt][reg] / lsum[reg]);
            }
    } else {
        // partial job: unnormalized f32 o + l to slot (t0==0 ? 0 : 1)
        float* op = (t0 == 0) ? o0w : o1w;
        const int tr0 = q0 - 1088 + wave * 16 + quad * 4;  // c>=17 -> q0>=1088
#pragma unroll
        for (int dt = 0; dt < 4; dt++)
#pragma unroll
            for (int reg = 0; reg < 4; reg++)
                op[((size_t)(b * 960 + tr0 + reg) << 10) + h * 64 + dt * 16 + lane15] =
                    o[dt][reg];
        if (lane15 == 0) {
            const int slot = (t0 == 0) ? 0 : 1;
            float* lp = lw + ((size_t)(slot * Bx + b) * Hx + h) * 960 + tr0;
#pragma unroll
            for (int reg = 0; reg < 4; reg++) lp[reg] = lsum[reg];
        }
    }
}

// ---------------- norm: combine split-K partials for rows t in [1088, 2048) ----------------
__global__ __launch_bounds__(256) void norm(const float* __restrict__ o0w,
                                            const float* __restrict__ o1w,
                                            const float* __restrict__ lw,
                                            __bf16* __restrict__ ctx) {
    const int r = blockIdx.x;            // 0..1919: (b, t-1088)
    const int b = r / 960, tr = r % 960;
    const int tid = threadIdx.x;
    const int h = tid >> 4;              // (tid*4)/64
    const size_t rowoff = ((size_t)(b * 960 + tr) << 10) + tid * 4;
    float4 a = *(const float4*)(o0w + rowoff);
    float4 c4 = *(const float4*)(o1w + rowoff);
    const float l0 = lw[((size_t)(0 * Bx + b) * Hx + h) * 960 + tr];
    const float l1 = lw[((size_t)(1 * Bx + b) * Hx + h) * 960 + tr];
    const float inv = 1.f / (l0 + l1);
    bf16x4 o;
    o[0] = (__bf16)((a.x + c4.x) * inv);
    o[1] = (__bf16)((a.y + c4.y) * inv);
    o[2] = (__bf16)((a.z + c4.z) * inv);
    o[3] = (__bf16)((a.w + c4.w) * inv);
    *(bf16x4*)(ctx + (((size_t)(b * Tx + 1088 + tr)) << 10) + tid * 4) = o;
}

extern "C" void kernel_launch(void* const* d_in, const int* in_sizes, int n_in,
                              void* d_out, int out_size, void* d_ws, size_t ws_size,
                              hipStream_t stream) {
    const float* x  = (const float*)d_in[0];
    const float* Wq = (const float*)d_in[1];
    const float* Wk = (const float*)d_in[2];
    const float* Wv = (const float*)d_in[3];
    const float* Wo = (const float*)d_in[4];
    const float* bo = (const float*)d_in[5];
    float* out = (float*)d_out;

    char* ws = (char*)d_ws;
    __bf16* xb  = (__bf16*)(ws + 0);                 // 8 MB
    __bf16* Wt  = (__bf16*)(ws + (8ull << 20));      // 4 x 2 MB
    __bf16* Qb  = (__bf16*)(ws + (16ull << 20));     // 8 MB [B,H,T,DH] (pre-scaled 0.125*log2e)
    __bf16* Kb  = (__bf16*)(ws + (24ull << 20));     // 8 MB [B,H,T,DH]
    __bf16* Vtg = (__bf16*)(ws + (32ull << 20));     // 8 MB [B,H,DH,T]
    __bf16* ctx = (__bf16*)(ws + (40ull << 20));     // 8 MB [B,T,H,DH]
    float*  o0w = (float*)(ws + (48ull << 20));      // 7.9 MB [B,960,1024] f32
    float*  o1w = (float*)(ws + (56ull << 20));      // 7.9 MB
    float*  lw  = (float*)(ws + (64ull << 20));      // 0.25 MB [2,B,H,960] f32

    prep<<<dim3(16, 16, 5), 256, 0, stream>>>(x, Wq, Wk, Wv, Wo, xb, Wt);

    gemm_qkv<<<dim3(Bx * Tx / 128, 3 * Dx / 128), 256, 0, stream>>>(xb, Wt, Qb, Kb, Vtg);

    attn_mfma<<<dim3(1504), 256, 0, stream>>>(Qb, Kb, Vtg, ctx, o0w, o1w, lw);

    norm<<<dim3(1920), 256, 0, stream>>>(o0w, o1w, lw, ctx);

    gemm_out<<<dim3(Bx * Tx / 128, Dx / 64), 256, 0, stream>>>(ctx, Wt + 3 * (1u << 20), out, bo);
}

// Round 15
// 169.330 us; speedup vs baseline: 1.0552x; 1.0552x over previous
//
#include <hip/hip_runtime.h>
#include <hip/hip_bf16.h>

// MHA: B=2, T=2048, D=1024, H=16, DH=64. fp32 in/out, bf16 MFMA internal.
// R26 = revert to R24 (verified session best, 170.1us). R25's bundled XCD
//      remaps regressed -8.6us (gemm chunked remap traded B-panel duplication
//      for A-churn; default round-robin already had the better locality).
// R24 = stack of the two verified attn levers:
//      - R23 XOR-swizzled LDS (conflicts 4.87M -> ~1M)
//      - R18 split-K job table (occupancy ~6 blocks/CU uniform, max job 17 tiles)
//      partial jobs write f32 o+l, separate norm combines (no device fences).

typedef __bf16 bf16x8 __attribute__((ext_vector_type(8)));
typedef __bf16 bf16x4 __attribute__((ext_vector_type(4)));
typedef float  f32x4  __attribute__((ext_vector_type(4)));

#define Bx 2
#define Tx 2048
#define Dx 1024
#define Hx 16
#define DHx 64

// job table: {chunk, firstTile, nTiles}, descending nTiles. 47 jobs per (b,h).
// chunks 0..16: single job (c+1 tiles). chunks 17..31: split ceil/floor halves.
__device__ __constant__ unsigned char JTAB[47][3] = {
    {16, 0, 17},
    {31, 0, 16}, {31, 16, 16}, {30, 0, 16}, {15, 0, 16},
    {30, 16, 15}, {29, 0, 15}, {29, 15, 15}, {28, 0, 15}, {14, 0, 15},
    {28, 15, 14}, {27, 0, 14}, {27, 14, 14}, {26, 0, 14}, {13, 0, 14},
    {26, 14, 13}, {25, 0, 13}, {25, 13, 13}, {24, 0, 13}, {12, 0, 13},
    {24, 13, 12}, {23, 0, 12}, {23, 12, 12}, {22, 0, 12}, {11, 0, 12},
    {22, 12, 11}, {21, 0, 11}, {21, 11, 11}, {20, 0, 11}, {10, 0, 11},
    {20, 11, 10}, {19, 0, 10}, {19, 10, 10}, {18, 0, 10}, {9, 0, 10},
    {18, 10, 9}, {17, 0, 9}, {17, 9, 9}, {8, 0, 9},
    {7, 0, 8}, {6, 0, 7}, {5, 0, 6}, {4, 0, 5}, {3, 0, 4}, {2, 0, 3},
    {1, 0, 2}, {0, 0, 1}
};

// ---------------- prep: z=0 -> x fp32->bf16; z=1..4 -> W transpose+cvt ----------------
__global__ __launch_bounds__(256) void prep(const float* __restrict__ x,
                                            const float* __restrict__ W0,
                                            const float* __restrict__ W1,
                                            const float* __restrict__ W2,
                                            const float* __restrict__ W3,
                                            __bf16* __restrict__ xb,
                                            __bf16* __restrict__ Wt) {
    const int z = blockIdx.z;
    if (z == 0) {
        const int blk = blockIdx.y * 16 + blockIdx.x;
        const float* xp = x + (size_t)blk * 16384;
        __bf16* xo = xb + (size_t)blk * 16384;
#pragma unroll
        for (int i = 0; i < 16; i++) {
            float4 v = *(const float4*)(xp + i * 1024 + threadIdx.x * 4);
            bf16x4 o;
            o[0] = (__bf16)v.x; o[1] = (__bf16)v.y; o[2] = (__bf16)v.z; o[3] = (__bf16)v.w;
            *(bf16x4*)(xo + i * 1024 + threadIdx.x * 4) = o;
        }
        return;
    }
    __shared__ float tile[64][65];
    const float* W = (z == 1) ? W0 : (z == 2) ? W1 : (z == 3) ? W2 : W3;
    __bf16* o = Wt + (size_t)(z - 1) * Dx * Dx;
    int k0 = blockIdx.x * 64, n0 = blockIdx.y * 64;
    int t = threadIdx.x;
    int cc = t & 63, rbase = t >> 6;
#pragma unroll
    for (int i = 0; i < 16; i++) {
        int rr = rbase + i * 4;
        tile[rr][cc] = W[(size_t)(k0 + rr) * Dx + n0 + cc];
    }
    __syncthreads();
#pragma unroll
    for (int i = 0; i < 16; i++) {
        int rr = rbase + i * 4;
        o[(size_t)(n0 + rr) * Dx + k0 + cc] = (__bf16)tile[cc][rr];
    }
}

static __device__ __forceinline__ void gload16(const __bf16* g, __bf16* l) {
    __builtin_amdgcn_global_load_lds((const __attribute__((address_space(1))) void*)g,
                                     (__attribute__((address_space(3))) void*)l, 16, 0, 0);
}

// swizzled LDS address: [row][colByte] with byte-XOR (row&7)<<4; rows are 128B.
static __device__ __forceinline__ char* swzp(char* base, int row, int colByte) {
    return base + row * 128 + (colByte ^ ((row & 7) << 4));
}

// ---------------- fused QKV GEMM: [4096 x 3072] = xb @ [WqT;WkT;WvT]^T ----------------
// 128x128 tile, BK=64 as 2 BK=32 halves. 4 waves, each owns a 64x64 quadrant.
__global__ __launch_bounds__(256, 3) void gemm_qkv(const __bf16* __restrict__ A,
                                                   const __bf16* __restrict__ BT,
                                                   __bf16* __restrict__ Qb,
                                                   __bf16* __restrict__ Kb,
                                                   __bf16* __restrict__ Vt) {
    __shared__ __bf16 As[2][128 * 32];  // 16 KB (two k-halves)
    __shared__ __bf16 Bs[2][128 * 32];  // 16 KB
    __shared__ __bf16 Vbuf[64 * 136];   // 17 KB epilogue transpose (z==2)
    const int t = threadIdx.x;
    const int lane = t & 63, wave = t >> 6;
    const int lane15 = lane & 15, quad = lane >> 4;
    const int m0 = blockIdx.x * 128, n0 = blockIdx.y * 128;
    const int wm = wave & 1, wn = wave >> 1;

    const int sr = wave * 16 + (lane >> 2);  // 0..63 (pass 0); pass 1 adds 64
    const int sc = (lane & 3) * 8;
    const __bf16* Ag = A + (size_t)(m0 + sr) * Dx + sc;
    const __bf16* Bg = BT + (size_t)(n0 + sr) * Dx + sc;
    __bf16* As00 = &As[0][(wave * 16) * 32];
    __bf16* As01 = &As[0][(64 + wave * 16) * 32];
    __bf16* As10 = &As[1][(wave * 16) * 32];
    __bf16* As11 = &As[1][(64 + wave * 16) * 32];
    __bf16* Bs00 = &Bs[0][(wave * 16) * 32];
    __bf16* Bs01 = &Bs[0][(64 + wave * 16) * 32];
    __bf16* Bs10 = &Bs[1][(wave * 16) * 32];
    __bf16* Bs11 = &Bs[1][(64 + wave * 16) * 32];

    f32x4 acc[4][4];
#pragma unroll
    for (int i = 0; i < 4; i++)
#pragma unroll
        for (int j = 0; j < 4; j++) acc[i][j] = (f32x4){0.f, 0.f, 0.f, 0.f};

    for (int k0 = 0; k0 < Dx; k0 += 64) {
        gload16(Ag, As00);
        gload16(Ag + 64 * Dx, As01);
        gload16(Ag + 32, As10);
        gload16(Ag + 64 * Dx + 32, As11);
        gload16(Bg, Bs00);
        gload16(Bg + 64 * Dx, Bs01);
        gload16(Bg + 32, Bs10);
        gload16(Bg + 64 * Dx + 32, Bs11);
        Ag += 64; Bg += 64;
        __syncthreads();
#pragma unroll
        for (int half = 0; half < 2; half++) {
            bf16x8 af[4], bfr[4];
#pragma unroll
            for (int i = 0; i < 4; i++)
                af[i] = *(const bf16x8*)&As[half][(wm * 64 + i * 16 + lane15) * 32 + quad * 8];
#pragma unroll
            for (int j = 0; j < 4; j++)
                bfr[j] = *(const bf16x8*)&Bs[half][(wn * 64 + j * 16 + lane15) * 32 + quad * 8];
#pragma unroll
            for (int mt = 0; mt < 4; mt++)
#pragma unroll
                for (int nt = 0; nt < 4; nt++)
                    acc[mt][nt] = __builtin_amdgcn_mfma_f32_16x16x32_bf16(af[mt], bfr[nt], acc[mt][nt], 0, 0, 0);
        }
        __syncthreads();
    }

    const int z = n0 >> 10;  // block n-range lies in one z (128 | 1024)
    if (z < 2) {
        __bf16* outp = z ? Kb : Qb;
        // Q pre-scaled by 0.125 * log2(e) so attn can use exp2 directly.
        const float scale = z ? 1.0f : 0.18033688011112042f;
#pragma unroll
        for (int mt = 0; mt < 4; mt++)
#pragma unroll
            for (int nt = 0; nt < 4; nt++) {
                const int cc = (n0 + wn * 64 + nt * 16 + lane15) & 1023;
                const int h = cc >> 6, dh = cc & 63;
#pragma unroll
                for (int r4 = 0; r4 < 4; r4++) {
                    const int row = m0 + wm * 64 + mt * 16 + quad * 4 + r4;
                    const int b = row >> 11, tt = row & 2047;
                    outp[(((size_t)(b * Hx + h) * Tx + tt) << 6) + dh] =
                        (__bf16)(acc[mt][nt][r4] * scale);
                }
            }
    } else {
        // V^T epilogue via LDS transpose: coalesced 64B-per-thread stores.
        const int bq = m0 >> 11;
        const int tt0 = m0 & 2047;
#pragma unroll
        for (int p = 0; p < 2; p++) {
            if (p) __syncthreads();  // pass-0 readers done before buffer reuse
            if (wn == p) {
#pragma unroll
                for (int mt = 0; mt < 4; mt++)
#pragma unroll
                    for (int nt = 0; nt < 4; nt++) {
                        bf16x4 v4;
#pragma unroll
                        for (int r4 = 0; r4 < 4; r4++) v4[r4] = (__bf16)acc[mt][nt][r4];
                        *(bf16x4*)&Vbuf[(nt * 16 + lane15) * 136 + wm * 64 + mt * 16 + quad * 4] = v4;
                    }
            }
            __syncthreads();  // tile visible
            const int row = t >> 2;          // 0..63: local column (dh-line)
            const int part = (t & 3) * 32;   // 32 elems = 64B per thread
            const int cf = (n0 + p * 64 + row) & 1023;
            const int h = cf >> 6, dh = cf & 63;
            __bf16* dst = Vt + ((size_t)(bq * Hx + h) * DHx + dh) * Tx + tt0 + part;
            const __bf16* srcl = &Vbuf[row * 136 + part];
#pragma unroll
            for (int i = 0; i < 4; i++)
                *(bf16x8*)(dst + i * 8) = *(const bf16x8*)(srcl + i * 8);
        }
    }
}

// ---------------- output GEMM: out[4096 x 1024] = ctx @ Wo + bo ----------------
__global__ __launch_bounds__(256, 2) void gemm_out(const __bf16* __restrict__ A,
                                                   const __bf16* __restrict__ BT,
                                                   float* __restrict__ outf,
                                                   const float* __restrict__ bias) {
    __shared__ __bf16 As[2][128 * 32];  // 16 KB
    __shared__ __bf16 Bs[2][64 * 32];   // 8 KB
    const int t = threadIdx.x;
    const int lane = t & 63, wave = t >> 6;
    const int lane15 = lane & 15, quad = lane >> 4;
    const int m0 = blockIdx.x * 128, n0 = blockIdx.y * 64;
    const int wm = wave & 1, wn = wave >> 1;

    const int sr = wave * 16 + (lane >> 2), sc = (lane & 3) * 8;
    const __bf16* Ag = A + (size_t)(m0 + sr) * Dx + sc;
    const __bf16* Bg = BT + (size_t)(n0 + sr) * Dx + sc;
    __bf16* As00 = &As[0][(wave * 16) * 32];
    __bf16* As01 = &As[0][(64 + wave * 16) * 32];
    __bf16* As10 = &As[1][(wave * 16) * 32];
    __bf16* As11 = &As[1][(64 + wave * 16) * 32];
    __bf16* Bs0  = &Bs[0][(wave * 16) * 32];
    __bf16* Bs1  = &Bs[1][(wave * 16) * 32];

    f32x4 acc[4][2];
#pragma unroll
    for (int i = 0; i < 4; i++)
#pragma unroll
        for (int j = 0; j < 2; j++) acc[i][j] = (f32x4){0.f, 0.f, 0.f, 0.f};

    for (int k0 = 0; k0 < Dx; k0 += 64) {
        gload16(Ag, As00);
        gload16(Ag + 64 * Dx, As01);
        gload16(Ag + 32, As10);
        gload16(Ag + 64 * Dx + 32, As11);
        gload16(Bg, Bs0);
        gload16(Bg + 32, Bs1);
        Ag += 64; Bg += 64;
        __syncthreads();
#pragma unroll
        for (int half = 0; half < 2; half++) {
            bf16x8 af[4], bfr[2];
#pragma unroll
            for (int i = 0; i < 4; i++)
                af[i] = *(const bf16x8*)&As[half][(wm * 64 + i * 16 + lane15) * 32 + quad * 8];
#pragma unroll
            for (int j = 0; j < 2; j++)
                bfr[j] = *(const bf16x8*)&Bs[half][(wn * 32 + j * 16 + lane15) * 32 + quad * 8];
#pragma unroll
            for (int mt = 0; mt < 4; mt++)
#pragma unroll
                for (int nt = 0; nt < 2; nt++)
                    acc[mt][nt] = __builtin_amdgcn_mfma_f32_16x16x32_bf16(af[mt], bfr[nt], acc[mt][nt], 0, 0, 0);
        }
        __syncthreads();
    }

#pragma unroll
    for (int mt = 0; mt < 4; mt++)
#pragma unroll
        for (int nt = 0; nt < 2; nt++) {
            const int col = n0 + wn * 32 + nt * 16 + lane15;
#pragma unroll
            for (int r4 = 0; r4 < 4; r4++) {
                const int row = m0 + wm * 64 + mt * 16 + quad * 4 + r4;
                outf[(size_t)row * Dx + col] = acc[mt][nt][r4] + bias[col];
            }
        }
}

// ---------------- MFMA flash attention: split-K jobs, XOR-swizzled LDS ----------------
__global__ __launch_bounds__(256) void attn_mfma(const __bf16* __restrict__ Q,
                                                 const __bf16* __restrict__ K,
                                                 const __bf16* __restrict__ Vt,
                                                 __bf16* __restrict__ ctx,
                                                 float* __restrict__ o0w,
                                                 float* __restrict__ o1w,
                                                 float* __restrict__ lw) {
    __shared__ __bf16 Ks[64 * 64];   // [key][d]   8 KB, swizzled
    __shared__ __bf16 Vs[64 * 64];   // [d][key]   8 KB, swizzled
    __shared__ __bf16 Ps[64 * 64];   // [q][key]   8 KB, swizzled
    const int t = threadIdx.x;
    const int lane = t & 63, wave = t >> 6;
    const int lane15 = lane & 15, quad = lane >> 4;
    const int id = blockIdx.x;           // 0..1503
    const int j = id >> 5, bh = id & 31; // big jobs at low id -> resident first
    const int c = JTAB[j][0];
    const int t0 = JTAB[j][1];
    const int ktend = t0 + JTAB[j][2];
    const bool single = (t0 == 0) && (ktend == c + 1);
    const int b = bh >> 4, h = bh & 15;
    const int q0 = c * 64;
    const int qg = q0 + wave * 16 + quad * 4;
    const size_t headoff = ((size_t)(b * Hx + h)) * Tx * DHx;
    const __bf16* Kbase = K + headoff;   // [t][d]
    const __bf16* Vbase = Vt + headoff;  // [d][t]
    const int sr = t >> 2;               // staging row 0..63
    const int sce = (t & 3) * 16;        // staging col (elems)
    const int scB = sce * 2;
    char* KsB = (char*)Ks;
    char* VsB = (char*)Vs;
    char* PsB = (char*)Ps;

    bf16x8 qf0, qf1;
    {
        const __bf16* Qp = Q + headoff + (size_t)(q0 + wave * 16 + lane15) * 64 + quad * 8;
        qf0 = *(const bf16x8*)Qp;
        qf1 = *(const bf16x8*)(Qp + 32);
    }
    f32x4 o[4];
#pragma unroll
    for (int i = 0; i < 4; i++) o[i] = (f32x4){0.f, 0.f, 0.f, 0.f};
    float lpart[4] = {0.f, 0.f, 0.f, 0.f};

    bf16x8 kpre0, kpre1, vpre0, vpre1;
    {
        const __bf16* Kp = Kbase + (size_t)(t0 * 64 + sr) * 64 + sce;
        kpre0 = *(const bf16x8*)Kp; kpre1 = *(const bf16x8*)(Kp + 8);
        const __bf16* Vp = Vbase + (size_t)sr * Tx + t0 * 64 + sce;
        vpre0 = *(const bf16x8*)Vp; vpre1 = *(const bf16x8*)(Vp + 8);
    }

    for (int kt = t0; kt < ktend; kt++) {
        __syncthreads();  // prior tile's LDS reads complete
        *(bf16x8*)swzp(KsB, sr, scB)      = kpre0;
        *(bf16x8*)swzp(KsB, sr, scB + 16) = kpre1;
        *(bf16x8*)swzp(VsB, sr, scB)      = vpre0;
        *(bf16x8*)swzp(VsB, sr, scB + 16) = vpre1;
        if (kt + 1 < ktend) {
            const __bf16* Kp = Kbase + (size_t)((kt + 1) * 64 + sr) * 64 + sce;
            kpre0 = *(const bf16x8*)Kp; kpre1 = *(const bf16x8*)(Kp + 8);
            const __bf16* Vp = Vbase + (size_t)sr * Tx + (kt + 1) * 64 + sce;
            vpre0 = *(const bf16x8*)Vp; vpre1 = *(const bf16x8*)(Vp + 8);
        }
        __syncthreads();

        f32x4 s[4];
        __builtin_amdgcn_s_setprio(1);
#pragma unroll
        for (int nt = 0; nt < 4; nt++) {
            s[nt] = (f32x4){0.f, 0.f, 0.f, 0.f};
            bf16x8 b0 = *(const bf16x8*)swzp(KsB, nt * 16 + lane15, quad * 16);
            s[nt] = __builtin_amdgcn_mfma_f32_16x16x32_bf16(qf0, b0, s[nt], 0, 0, 0);
            bf16x8 b1 = *(const bf16x8*)swzp(KsB, nt * 16 + lane15, 64 + quad * 16);
            s[nt] = __builtin_amdgcn_mfma_f32_16x16x32_bf16(qf1, b1, s[nt], 0, 0, 0);
        }
        __builtin_amdgcn_s_setprio(0);

        if (kt == c) {
            // diagonal tile: causal mask active
            const int kbase = kt * 64;
#pragma unroll
            for (int nt = 0; nt < 4; nt++)
#pragma unroll
                for (int reg = 0; reg < 4; reg++) {
                    float e = __builtin_amdgcn_exp2f(s[nt][reg]);
                    if (kbase + nt * 16 + lane15 > qg + reg) e = 0.f;
                    lpart[reg] += e;
                    *(__bf16*)swzp(PsB, wave * 16 + quad * 4 + reg,
                                   (nt * 16 + lane15) * 2) = (__bf16)e;
                }
        } else {
            // interior tile: no masking possible
#pragma unroll
            for (int nt = 0; nt < 4; nt++)
#pragma unroll
                for (int reg = 0; reg < 4; reg++) {
                    float e = __builtin_amdgcn_exp2f(s[nt][reg]);
                    lpart[reg] += e;
                    *(__bf16*)swzp(PsB, wave * 16 + quad * 4 + reg,
                                   (nt * 16 + lane15) * 2) = (__bf16)e;
                }
        }

        bf16x8 pa0 = *(const bf16x8*)swzp(PsB, wave * 16 + lane15, quad * 16);
        bf16x8 pa1 = *(const bf16x8*)swzp(PsB, wave * 16 + lane15, 64 + quad * 16);
        __builtin_amdgcn_s_setprio(1);
#pragma unroll
        for (int dt = 0; dt < 4; dt++) {
            bf16x8 vb0 = *(const bf16x8*)swzp(VsB, dt * 16 + lane15, quad * 16);
            o[dt] = __builtin_amdgcn_mfma_f32_16x16x32_bf16(pa0, vb0, o[dt], 0, 0, 0);
            bf16x8 vb1 = *(const bf16x8*)swzp(VsB, dt * 16 + lane15, 64 + quad * 16);
            o[dt] = __builtin_amdgcn_mfma_f32_16x16x32_bf16(pa1, vb1, o[dt], 0, 0, 0);
        }
        __builtin_amdgcn_s_setprio(0);
    }

    // ---- row-sum of l across the 16-lane key groups ----
    float lsum[4];
#pragma unroll
    for (int reg = 0; reg < 4; reg++) {
        float l = lpart[reg];
#pragma unroll
        for (int off = 1; off < 16; off <<= 1) l += __shfl_xor(l, off);
        lsum[reg] = l;
    }

    if (single) {
        // chunks 0..16: full key range in this job -> normalized ctx write
#pragma unroll
        for (int dt = 0; dt < 4; dt++)
#pragma unroll
            for (int reg = 0; reg < 4; reg++) {
                int q = q0 + wave * 16 + quad * 4 + reg;
                ctx[(((size_t)(b * Tx + q)) * Hx + h) * 64 + dt * 16 + lane15] =
                    (__bf16)(o[dt][reg] / lsum[reg]);
            }
    } else {
        // partial job: unnormalized f32 o + l to slot (t0==0 ? 0 : 1)
        float* op = (t0 == 0) ? o0w : o1w;
        const int tr0 = q0 - 1088 + wave * 16 + quad * 4;  // c>=17 -> q0>=1088
#pragma unroll
        for (int dt = 0; dt < 4; dt++)
#pragma unroll
            for (int reg = 0; reg < 4; reg++)
                op[((size_t)(b * 960 + tr0 + reg) << 10) + h * 64 + dt * 16 + lane15] =
                    o[dt][reg];
        if (lane15 == 0) {
            const int slot = (t0 == 0) ? 0 : 1;
            float* lp = lw + ((size_t)(slot * Bx + b) * Hx + h) * 960 + tr0;
#pragma unroll
            for (int reg = 0; reg < 4; reg++) lp[reg] = lsum[reg];
        }
    }
}

// ---------------- norm: combine split-K partials for rows t in [1088, 2048) ----------------
__global__ __launch_bounds__(256) void norm(const float* __restrict__ o0w,
                                            const float* __restrict__ o1w,
                                            const float* __restrict__ lw,
                                            __bf16* __restrict__ ctx) {
    const int r = blockIdx.x;            // 0..1919: (b, t-1088)
    const int b = r / 960, tr = r % 960;
    const int tid = threadIdx.x;
    const int h = tid >> 4;              // (tid*4)/64
    const size_t rowoff = ((size_t)(b * 960 + tr) << 10) + tid * 4;
    float4 a = *(const float4*)(o0w + rowoff);
    float4 c4 = *(const float4*)(o1w + rowoff);
    const float l0 = lw[((size_t)(0 * Bx + b) * Hx + h) * 960 + tr];
    const float l1 = lw[((size_t)(1 * Bx + b) * Hx + h) * 960 + tr];
    const float inv = 1.f / (l0 + l1);
    bf16x4 o;
    o[0] = (__bf16)((a.x + c4.x) * inv);
    o[1] = (__bf16)((a.y + c4.y) * inv);
    o[2] = (__bf16)((a.z + c4.z) * inv);
    o[3] = (__bf16)((a.w + c4.w) * inv);
    *(bf16x4*)(ctx + (((size_t)(b * Tx + 1088 + tr)) << 10) + tid * 4) = o;
}

extern "C" void kernel_launch(void* const* d_in, const int* in_sizes, int n_in,
                              void* d_out, int out_size, void* d_ws, size_t ws_size,
                              hipStream_t stream) {
    const float* x  = (const float*)d_in[0];
    const float* Wq = (const float*)d_in[1];
    const float* Wk = (const float*)d_in[2];
    const float* Wv = (const float*)d_in[3];
    const float* Wo = (const float*)d_in[4];
    const float* bo = (const float*)d_in[5];
    float* out = (float*)d_out;

    char* ws = (char*)d_ws;
    __bf16* xb  = (__bf16*)(ws + 0);                 // 8 MB
    __bf16* Wt  = (__bf16*)(ws + (8ull << 20));      // 4 x 2 MB
    __bf16* Qb  = (__bf16*)(ws + (16ull << 20));     // 8 MB [B,H,T,DH] (pre-scaled 0.125*log2e)
    __bf16* Kb  = (__bf16*)(ws + (24ull << 20));     // 8 MB [B,H,T,DH]
    __bf16* Vtg = (__bf16*)(ws + (32ull << 20));     // 8 MB [B,H,DH,T]
    __bf16* ctx = (__bf16*)(ws + (40ull << 20));     // 8 MB [B,T,H,DH]
    float*  o0w = (float*)(ws + (48ull << 20));      // 7.9 MB [B,960,1024] f32
    float*  o1w = (float*)(ws + (56ull << 20));      // 7.9 MB
    float*  lw  = (float*)(ws + (64ull << 20));      // 0.25 MB [2,B,H,960] f32

    prep<<<dim3(16, 16, 5), 256, 0, stream>>>(x, Wq, Wk, Wv, Wo, xb, Wt);

    gemm_qkv<<<dim3(Bx * Tx / 128, 3 * Dx / 128), 256, 0, stream>>>(xb, Wt, Qb, Kb, Vtg);

    attn_mfma<<<dim3(1504), 256, 0, stream>>>(Qb, Kb, Vtg, ctx, o0w, o1w, lw);

    norm<<<dim3(1920), 256, 0, stream>>>(o0w, o1w, lw, ctx);

    gemm_out<<<dim3(Bx * Tx / 128, Dx / 64), 256, 0, stream>>>(ctx, Wt + 3 * (1u << 20), out, bo);
}